// Round 7
// baseline (386.869 us; speedup 1.0000x reference)
//
#include <hip/hip_runtime.h>
#include <hip/hip_bf16.h>
#include <math.h>

#define NTOK 49
#define KDIM 128
#define NH 4
#define QK_SCALE 0.17677669529663687f  // 32^-0.5

typedef __attribute__((ext_vector_type(8))) short bf16x8;
typedef __attribute__((ext_vector_type(4))) float f32x4;
typedef __attribute__((ext_vector_type(8))) unsigned short us8;

static __device__ __forceinline__ unsigned short f2bh(float f) {
    __hip_bfloat16 h = __float2bfloat16(f);          // HW RNE
    union { __hip_bfloat16 h; unsigned short u; } c; c.h = h; return c.u;
}
static __device__ __forceinline__ float b2f(unsigned short h) {
    union { unsigned int u; float f; } v; v.u = ((unsigned int)h) << 16;
    return v.f;
}
static __device__ __forceinline__ bf16x8 pack8(float4 a, float4 c) {
    bf16x8 r;
    r[0]=(short)f2bh(a.x); r[1]=(short)f2bh(a.y); r[2]=(short)f2bh(a.z); r[3]=(short)f2bh(a.w);
    r[4]=(short)f2bh(c.x); r[5]=(short)f2bh(c.y); r[6]=(short)f2bh(c.z); r[7]=(short)f2bh(c.w);
    return r;
}

// ---------------- single fused kernel: one block per window, ZERO prep ----------------
// LDS arena 76800 B -> 2 blocks/CU. Region timeline:
//   A [0,17408):     s_x [64][136] bf16 (phase 0-1a)
//                    -> tables after BA: mask bf16 [49][52] @0 (5120),
//                       rel u8 [49][52] @5120 (2560), bias_table f32 @7680 (2704)
//                    -> s_o [64][136] after B2.5 (tables dead)
//   B [17408,58368): s_qk per head: q[64][40] | k[64][40] (10240 B each);
//                    P [64][72] overlays own head's slot (9216 <= 10240, within-wave safe)
//   C [58368,76800): vt [4][32][72] bf16 (V transposed via MFMA D-layout)
__launch_bounds__(256, 2)
__global__ void k_solo(const float* __restrict__ x, const float* __restrict__ attn_mask,
                       const float* __restrict__ qkv_w, const float* __restrict__ qkv_b,
                       const float* __restrict__ proj_w, const float* __restrict__ proj_b,
                       const float* __restrict__ bias_table, const int* __restrict__ rel_index,
                       float* __restrict__ out, int nw) {
    __shared__ __align__(16) char arena[76800];
    unsigned short* s_x   = (unsigned short*)arena;            // [64][136]
    unsigned short* s_o   = (unsigned short*)arena;            // [64][136] (post B2.5)
    unsigned short* s_msk = (unsigned short*)arena;            // [49][52] bf16
    unsigned char*  s_rel = (unsigned char*)(arena + 5120);    // [49][52] u8
    float*          s_bt  = (float*)(arena + 7680);            // [169*4] f32
    unsigned short* s_qk  = (unsigned short*)(arena + 17408);  // [4][q|k]
    unsigned short* vt    = (unsigned short*)(arena + 58368);  // [4][32][72]

    const int b = blockIdx.x, t = threadIdx.x;
    const int lane = t & 63, wid = t >> 6;
    const int fr = lane & 15, fg = lane >> 4;
    const int wm = b % nw;
    const size_t gb = (size_t)b * NTOK;

    // ---- phase 0: stage x -> bf16 LDS; zero pad rows 49..63; issue table loads -> regs ----
    {
        const float4* xg = (const float4*)(x + gb * KDIM);
        for (int i = t; i < NTOK * 32; i += 256) {             // 1568 float4
            float4 v = xg[i];
            int row = i >> 5, col = (i & 31) * 4;
            ushort4 pk = { f2bh(v.x), f2bh(v.y), f2bh(v.z), f2bh(v.w) };
            *(ushort4*)&s_x[row * 136 + col] = pk;
        }
        if (t < 255) {                                          // pad rows (bytes >= 13328, above tables)
            int row = 49 + t / 17, c8 = (t % 17) * 8;
            *(us8*)&s_x[row * 136 + c8] = (us8){0,0,0,0,0,0,0,0};
        }
    }
    // table loads -> registers (latency hidden under B0/1a/1c)
    float mv[10]; int rv[10]; float btv[3];
    {
        const float* am = attn_mask + (size_t)wm * (NTOK * NTOK);
        #pragma unroll
        for (int it = 0; it < 10; ++it) {
            int idx = t + it * 256;
            mv[it] = 0.f; rv[it] = 0;
            if (idx < 49 * 52) {
                int q = idx / 52, k = idx - q * 52;
                if (k < NTOK) { mv[it] = am[q * NTOK + k]; rv[it] = rel_index[q * NTOK + k]; }
            }
        }
        #pragma unroll
        for (int it = 0; it < 3; ++it) {
            int i = t + it * 256;
            btv[it] = (i < 676) ? bias_table[i] : 0.f;
        }
    }
    __syncthreads();   // B0: s_x ready

    // ---- phase 1a: A-fragments of x ----
    bf16x8 ax[4][4];
    #pragma unroll
    for (int mt = 0; mt < 4; ++mt)
        #pragma unroll
        for (int ks = 0; ks < 4; ++ks)
            ax[mt][ks] = *(const bf16x8*)&s_x[(mt * 16 + fr) * 136 + ks * 32 + fg * 8];
    __syncthreads();   // BA: all s_x reads done -> region A reusable

    // ---- phase 1b: tables -> LDS ----
    #pragma unroll
    for (int it = 0; it < 10; ++it) {
        int idx = t + it * 256;
        if (idx < 49 * 52) { s_msk[idx] = f2bh(mv[it]); s_rel[idx] = (unsigned char)rv[it]; }
    }
    #pragma unroll
    for (int it = 0; it < 3; ++it) {
        int i = t + it * 256;
        if (i < 676) s_bt[i] = btv[it];
    }

    // ---- phase 1c: qkv GEMM, fp32 weights from global (L2-hot) + in-reg cvt ----
    #pragma unroll
    for (int i = 0; i < 6; ++i) {
        const int nt = wid * 6 + i;
        const int which = nt >> 3;            // 0=Q,1=K,2=V (wave-uniform)
        const int head = (nt >> 1) & 3;
        const int dbase = (nt & 1) * 16;
        const float* wr = qkv_w + (nt * 16 + fr) * KDIM;
        bf16x8 bw[4];
        #pragma unroll
        for (int ks = 0; ks < 4; ++ks) {
            float4 a = *(const float4*)(wr + ks * 32 + fg * 8);
            float4 c = *(const float4*)(wr + ks * 32 + fg * 8 + 4);
            if (which == 0) {
                a.x *= QK_SCALE; a.y *= QK_SCALE; a.z *= QK_SCALE; a.w *= QK_SCALE;
                c.x *= QK_SCALE; c.y *= QK_SCALE; c.z *= QK_SCALE; c.w *= QK_SCALE;
            }
            bw[ks] = pack8(a, c);
        }
        f32x4 acc[4];
        #pragma unroll
        for (int mt = 0; mt < 4; ++mt) acc[mt] = (f32x4){0.f, 0.f, 0.f, 0.f};
        #pragma unroll
        for (int ks = 0; ks < 4; ++ks)
            #pragma unroll
            for (int mt = 0; mt < 4; ++mt)
                acc[mt] = __builtin_amdgcn_mfma_f32_16x16x32_bf16(ax[mt][ks], bw[ks], acc[mt], 0, 0, 0);
        const float bias = qkv_b[nt * 16 + fr] * (which == 0 ? QK_SCALE : 1.f);
        if (which == 2) {
            unsigned short* base = vt + head * (32 * 72) + (dbase + fr) * 72;
            #pragma unroll
            for (int mt = 0; mt < 4; ++mt) {
                ushort4 pk = { f2bh(acc[mt][0] + bias), f2bh(acc[mt][1] + bias),
                               f2bh(acc[mt][2] + bias), f2bh(acc[mt][3] + bias) };
                *(ushort4*)&base[mt * 16 + fg * 4] = pk;
            }
        } else {
            unsigned short* base = s_qk + head * 5120 + (which == 1 ? 2560 : 0) + dbase + fr;
            #pragma unroll
            for (int mt = 0; mt < 4; ++mt)
                #pragma unroll
                for (int reg = 0; reg < 4; ++reg)
                    base[(mt * 16 + fg * 4 + reg) * 40] = f2bh(acc[mt][reg] + bias);
        }
    }
    __syncthreads();   // B1: q/k/vt + tables ready

    // ---- phase 2: swapped S^T = K Q^T (wave = head), softmax via LDS tables, P, PV ----
    f32x4 oacc[4][2];
    {
        unsigned short* q_h = s_qk + wid * 5120;
        unsigned short* k_h = q_h + 2560;

        bf16x8 bq4[4];
        #pragma unroll
        for (int qt = 0; qt < 4; ++qt)
            bq4[qt] = *(const bf16x8*)&q_h[(qt * 16 + fr) * 40 + fg * 8];

        f32x4 sacc[4][4];   // [kt][qt]: lane holds S[k=kt*16+fg*4+reg][q=qt*16+fr]
        #pragma unroll
        for (int kt = 0; kt < 4; ++kt) {
            bf16x8 ak = *(const bf16x8*)&k_h[(kt * 16 + fr) * 40 + fg * 8];
            #pragma unroll
            for (int qt = 0; qt < 4; ++qt)
                sacc[kt][qt] = __builtin_amdgcn_mfma_f32_16x16x32_bf16(ak, bq4[qt], (f32x4){0.f,0.f,0.f,0.f}, 0, 0, 0);
        }

        // softmax: bias/mask gathered from LDS tables
        #pragma unroll
        for (int qt = 0; qt < 4; ++qt) {
            const int qq = qt * 16 + fr;
            const int mrow = ((qq <= 48) ? qq : 48) * 52;
            float vv[4][4];
            float mx = -1e30f;
            #pragma unroll
            for (int kt = 0; kt < 4; ++kt) {
                const int kb = kt * 16 + fg * 4;
                const unsigned int relw = *(const unsigned int*)&s_rel[mrow + kb];
                const ushort4 mw = *(const ushort4*)&s_msk[mrow + kb];
                #pragma unroll
                for (int reg = 0; reg < 4; ++reg) {
                    const int kk = kb + reg;
                    const unsigned short mhalf = (reg == 0) ? mw.x : (reg == 1) ? mw.y : (reg == 2) ? mw.z : mw.w;
                    float s = sacc[kt][qt][reg]
                            + s_bt[((relw >> (8 * reg)) & 0xffu) * NH + wid]
                            + b2f(mhalf);
                    vv[kt][reg] = (kk <= 48) ? s : -1e30f;
                    mx = fmaxf(mx, vv[kt][reg]);
                }
            }
            mx = fmaxf(mx, __shfl_xor(mx, 16));
            mx = fmaxf(mx, __shfl_xor(mx, 32));
            float sum = 0.f;
            #pragma unroll
            for (int kt = 0; kt < 4; ++kt)
                #pragma unroll
                for (int reg = 0; reg < 4; ++reg) {
                    float e = __expf(vv[kt][reg] - mx);
                    vv[kt][reg] = e;
                    sum += e;
                }
            sum += __shfl_xor(sum, 16);
            sum += __shfl_xor(sum, 32);
            const float r = 1.f / sum;
            #pragma unroll
            for (int kt = 0; kt < 4; ++kt)
                #pragma unroll
                for (int reg = 0; reg < 4; ++reg)
                    sacc[kt][qt][reg] = vv[kt][reg] * r;
        }

        // P -> own head's LDS slot (within-wave overlay of q|k; fits in 10240 B slot)
        unsigned short* p_h = q_h;   // [64][72]
        #pragma unroll
        for (int qt = 0; qt < 4; ++qt)
            #pragma unroll
            for (int kt = 0; kt < 4; ++kt) {
                ushort4 pk = { f2bh(sacc[kt][qt][0]), f2bh(sacc[kt][qt][1]),
                               f2bh(sacc[kt][qt][2]), f2bh(sacc[kt][qt][3]) };
                *(ushort4*)&p_h[(qt * 16 + fr) * 72 + kt * 16 + fg * 4] = pk;
            }

        // PV
        const unsigned short* vt_h = vt + wid * (32 * 72);
        bf16x8 bv[2][2];
        #pragma unroll
        for (int ni = 0; ni < 2; ++ni)
            #pragma unroll
            for (int ks = 0; ks < 2; ++ks)
                bv[ni][ks] = *(const bf16x8*)&vt_h[(ni * 16 + fr) * 72 + ks * 32 + fg * 8];
        #pragma unroll
        for (int mt = 0; mt < 4; ++mt) {
            oacc[mt][0] = (f32x4){0.f,0.f,0.f,0.f};
            oacc[mt][1] = (f32x4){0.f,0.f,0.f,0.f};
            #pragma unroll
            for (int ks = 0; ks < 2; ++ks) {
                bf16x8 ap = *(const bf16x8*)&p_h[(mt * 16 + fr) * 72 + ks * 32 + fg * 8];
                #pragma unroll
                for (int ni = 0; ni < 2; ++ni)
                    oacc[mt][ni] = __builtin_amdgcn_mfma_f32_16x16x32_bf16(ap, bv[ni][ks], oacc[mt][ni], 0, 0, 0);
            }
        }
    }
    __syncthreads();   // B2.5: all table reads done -> s_o overlay of region A is safe

    #pragma unroll
    for (int mt = 0; mt < 4; ++mt)
        #pragma unroll
        for (int ni = 0; ni < 2; ++ni)
            #pragma unroll
            for (int reg = 0; reg < 4; ++reg)
                s_o[(mt * 16 + fg * 4 + reg) * 136 + wid * 32 + ni * 16 + fr] = f2bh(oacc[mt][ni][reg]);
    __syncthreads();   // B3: s_o complete

    // ---- phase 3: out = o @ proj_w^T + proj_b (fp32 proj weights inline, L2-hot) ----
    {
        bf16x8 ao[4][4];
        #pragma unroll
        for (int mt = 0; mt < 4; ++mt)
            #pragma unroll
            for (int ks = 0; ks < 4; ++ks)
                ao[mt][ks] = *(const bf16x8*)&s_o[(mt * 16 + fr) * 136 + ks * 32 + fg * 8];
        #pragma unroll
        for (int i = 0; i < 2; ++i) {
            const int nt = wid * 2 + i;
            const float* wr = proj_w + (nt * 16 + fr) * KDIM;
            bf16x8 pw[4];
            #pragma unroll
            for (int ks = 0; ks < 4; ++ks) {
                float4 a = *(const float4*)(wr + ks * 32 + fg * 8);
                float4 c = *(const float4*)(wr + ks * 32 + fg * 8 + 4);
                pw[ks] = pack8(a, c);
            }
            f32x4 acc[4];
            #pragma unroll
            for (int mt = 0; mt < 4; ++mt) acc[mt] = (f32x4){0.f,0.f,0.f,0.f};
            #pragma unroll
            for (int ks = 0; ks < 4; ++ks)
                #pragma unroll
                for (int mt = 0; mt < 4; ++mt)
                    acc[mt] = __builtin_amdgcn_mfma_f32_16x16x32_bf16(ao[mt][ks], pw[ks], acc[mt], 0, 0, 0);
            const float pbv = proj_b[nt * 16 + fr];
            #pragma unroll
            for (int mt = 0; mt < 4; ++mt)
                #pragma unroll
                for (int reg = 0; reg < 4; ++reg) {
                    const int tok = mt * 16 + fg * 4 + reg;
                    if (tok < NTOK)
                        out[(gb + tok) * KDIM + nt * 16 + fr] = acc[mt][reg] + pbv;
                }
        }
    }
}

extern "C" void kernel_launch(void* const* d_in, const int* in_sizes, int n_in,
                              void* d_out, int out_size, void* d_ws, size_t ws_size,
                              hipStream_t stream) {
    const float* x          = (const float*)d_in[0];
    const float* attn_mask  = (const float*)d_in[1];
    const float* qkv_w      = (const float*)d_in[2];
    const float* qkv_b      = (const float*)d_in[3];
    const float* proj_w     = (const float*)d_in[4];
    const float* proj_b     = (const float*)d_in[5];
    const float* bias_table = (const float*)d_in[6];
    const int*   rel_index  = (const int*)d_in[7];
    float* out = (float*)d_out;

    const int B  = in_sizes[0] / (NTOK * KDIM);           // 4096
    int nw = in_sizes[1] / (NTOK * NTOK);                 // 64
    if (nw <= 0) nw = 1;

    k_solo<<<dim3(B), dim3(256), 0, stream>>>(
        x, attn_mask, qkv_w, qkv_b, proj_w, proj_b, bias_table, rel_index, out, nw);
}